// Round 13
// baseline (168.497 us; speedup 1.0000x reference)
//
#include <hip/hip_runtime.h>
#include <math.h>

#define HEADS 4
#define DIM 128
#define NG 8      // XCD-partitioned bucket groups
#define CAPG 32   // slots per (group, node); per-group degree ~Poisson(2)

typedef __bf16 bf16x8 __attribute__((ext_vector_type(8)));
typedef float f32x4 __attribute__((ext_vector_type(4)));

__device__ __forceinline__ unsigned short f2bf(float x) {
    unsigned u = __float_as_uint(x);
    unsigned r = (u + 0x7FFFu + ((u >> 16) & 1u)) >> 16;  // RNE
    return (unsigned short)r;
}
__device__ __forceinline__ float bf2f(unsigned short v) {
    return __uint_as_float(((unsigned)v) << 16);
}

// ---- K0: W -> W16 (bf16), 64 KB, 16 blocks ----
__global__ __launch_bounds__(256) void k_cvtW(const float* __restrict__ W,
                                              unsigned short* __restrict__ W16) {
    int j = blockIdx.x * 256 + threadIdx.x;  // 4096 float4s
    float4 v = ((const float4*)W)[j];
    ushort4 us;
    us.x = f2bf(v.x); us.y = f2bf(v.y); us.z = f2bf(v.z); us.w = f2bf(v.w);
    ((ushort4*)W16)[j] = us;
}

// ---- K1: grid = NBR MFMA blocks + EB edge blocks (co-scheduled, one launch) ----
// MFMA blocks (bid < NBR): h16 = bf16(ent @ W^T), s1/s3 epilogue.
// Edge blocks: fill XCD-local sub-bucket g = bid&7 (1024 edges/block, 4/thread).
__global__ __launch_bounds__(256) void k_proj(const float* __restrict__ ent,
                                              const unsigned short* __restrict__ W16,
                                              const float* __restrict__ aw,
                                              const int* __restrict__ ei,
                                              const int* __restrict__ et,
                                              unsigned short* __restrict__ h16,
                                              float4* __restrict__ s1,
                                              float4* __restrict__ s3,
                                              int* __restrict__ cnt,
                                              int* __restrict__ packed,
                                              int N, int E, int NBR) {
    int t = threadIdx.x;
    int bid = blockIdx.x;
    if (bid >= NBR) {
        // -------- edge block: sub-bucket scatter fill --------
        int g = bid & (NG - 1);   // heuristic: bid%8 ~ XCD id (locality only)
        int eb = bid - NBR;
        int e0 = eb * 1024;
        int dn[4], pk[4];
        bool vl[4];
#pragma unroll
        for (int j = 0; j < 4; ++j) {
            int e = e0 + j * 256 + t;
            vl[j] = e < E;
            int ec = vl[j] ? e : 0;
            dn[j] = ei[E + ec];
            pk[j] = (ei[ec] << 6) | et[ec];
        }
        int pos[4];
#pragma unroll
        for (int j = 0; j < 4; ++j)
            if (vl[j]) pos[j] = atomicAdd(&cnt[(size_t)g * N + dn[j]], 1);
#pragma unroll
        for (int j = 0; j < 4; ++j)
            if (vl[j]) {
                int p = pos[j] < CAPG ? pos[j] : CAPG - 1;  // safety; ~never hit
                packed[((size_t)g * N + dn[j]) * CAPG + p] = pk[j];
            }
        return;
    }
    // -------- MFMA block --------
    int wv = t >> 6, lane = t & 63, ln = lane & 15, quad = lane >> 4;
    int er = bid * 64 + wv * 16 + ln;
    int erc = er < N ? er : N - 1;
    const float4* ent4 = (const float4*)ent;
    bf16x8 bfr[4];
#pragma unroll
    for (int ks = 0; ks < 4; ++ks) {
        float4 a0 = ent4[(size_t)erc * 32 + ks * 8 + quad * 2];
        float4 a1 = ent4[(size_t)erc * 32 + ks * 8 + quad * 2 + 1];
        bf16x8 f;
        f[0] = (__bf16)a0.x; f[1] = (__bf16)a0.y; f[2] = (__bf16)a0.z; f[3] = (__bf16)a0.w;
        f[4] = (__bf16)a1.x; f[5] = (__bf16)a1.y; f[6] = (__bf16)a1.z; f[7] = (__bf16)a1.w;
        bfr[ks] = f;
    }
    f32x4 acc[8];
#pragma unroll
    for (int mt = 0; mt < 8; ++mt) acc[mt] = (f32x4){0.f, 0.f, 0.f, 0.f};
#pragma unroll
    for (int ks = 0; ks < 4; ++ks) {
#pragma unroll
        for (int mt = 0; mt < 8; ++mt) {
            bf16x8 afr = *(const bf16x8*)&W16[(mt * 16 + ln) * DIM + ks * 32 + quad * 8];
            acc[mt] = __builtin_amdgcn_mfma_f32_16x16x32_bf16(afr, bfr[ks], acc[mt], 0, 0, 0);
        }
    }
    // D layout: col(entity row)=lane&15, row(dim)=mt*16+quad*4+reg
    const float4* awv = (const float4*)aw;
    float s1h[4] = {0.f, 0.f, 0.f, 0.f}, s3h[4] = {0.f, 0.f, 0.f, 0.f};
#pragma unroll
    for (int mt = 0; mt < 8; ++mt) {
        int d0 = mt * 16 + quad * 4;
        if (er < N) {
            ushort4 us;
            us.x = f2bf(acc[mt][0]); us.y = f2bf(acc[mt][1]);
            us.z = f2bf(acc[mt][2]); us.w = f2bf(acc[mt][3]);
            *(ushort4*)&h16[(size_t)er * DIM + d0] = us;
        }
        int wi = (mt & 1) * 4 + quad;  // (d0 % 32) / 4 — same aw for every head
        float4 w1 = awv[wi], w3 = awv[16 + wi];
        int hh = mt >> 1;
        s1h[hh] += acc[mt][0] * w1.x + acc[mt][1] * w1.y + acc[mt][2] * w1.z + acc[mt][3] * w1.w;
        s3h[hh] += acc[mt][0] * w3.x + acc[mt][1] * w3.y + acc[mt][2] * w3.z + acc[mt][3] * w3.w;
    }
#pragma unroll
    for (int hh = 0; hh < HEADS; ++hh) {
        s1h[hh] += __shfl_xor(s1h[hh], 16);
        s1h[hh] += __shfl_xor(s1h[hh], 32);
        s3h[hh] += __shfl_xor(s3h[hh], 16);
        s3h[hh] += __shfl_xor(s3h[hh], 32);
    }
    if (quad == 0 && er < N) {
        s1[er] = make_float4(s1h[0], s1h[1], s1h[2], s1h[3]);
        s3[er] = make_float4(s3h[0], s3h[1], s3h[2], s3h[3]);
    }
}

// ---- K2: s2[rel,hh]; v recomputed per block in LDS ----
__global__ __launch_bounds__(256) void k_s2(const float* __restrict__ rel,
                                            const float* __restrict__ Wr,
                                            const float* __restrict__ aw,
                                            float* __restrict__ s2, int RH) {
    __shared__ float v[DIM * HEADS];
    int t = threadIdx.x;
    for (int i = t; i < DIM * HEADS; i += 256) {
        int k = i >> 2, hh = i & 3;
        float a = 0.f;
        for (int j = 0; j < 32; ++j) a += Wr[(hh * 32 + j) * DIM + k] * aw[32 + j];
        v[i] = a;  // i == k*4+hh
    }
    __syncthreads();
    int o = blockIdx.x * 4 + (t >> 6);
    if (o >= RH) return;
    int r = o >> 2, hh = o & 3;
    int l = t & 63;
    float p = rel[r * DIM + l] * v[l * 4 + hh] + rel[r * DIM + 64 + l] * v[(64 + l) * 4 + hh];
#pragma unroll
    for (int off = 32; off > 0; off >>= 1) p += __shfl_down(p, off);
    if (l == 0) s2[o] = p;
}

// ---- K3: gather per destination node; compact 8 sub-buckets into LDS list ----
__global__ __launch_bounds__(64) void k_out(const int* __restrict__ packed,
                                            const int* __restrict__ cnt,
                                            const float4* __restrict__ s1,
                                            const float4* __restrict__ s2,
                                            const float4* __restrict__ s3,
                                            const float* __restrict__ ab,
                                            const unsigned short* __restrict__ h16,
                                            float* __restrict__ out, int N) {
    __shared__ int src_l[NG * CAPG];
    __shared__ float es_l[NG * CAPG * 4];
    int n = blockIdx.x;
    int t = threadIdx.x;  // 0..63, handles dims 2t, 2t+1
    int hh = t >> 4;
    float b = ab[0];
    float4 s3n = s3[n];
    int cg[NG], pf[NG];
    int tot = 0;
#pragma unroll
    for (int g = 0; g < NG; ++g) {
        int c = cnt[(size_t)g * N + n];
        if (c > CAPG) c = CAPG;
        cg[g] = c;
        pf[g] = tot;
        tot += c;
    }
    // stage + score: position p -> (group, slot)
    for (int p = t; p < tot; p += 64) {
        int g = 0;
#pragma unroll
        for (int gg = 1; gg < NG; ++gg)
            if (p >= pf[gg]) g = gg;
        int pk = packed[((size_t)g * N + n) * CAPG + (p - pf[g])];
        int s = pk >> 6, ty = pk & 63;
        float4 a = s1[s], cc = s2[ty];
        float4 sc;
        sc.x = a.x + cc.x + s3n.x + b;
        sc.y = a.y + cc.y + s3n.y + b;
        sc.z = a.z + cc.z + s3n.z + b;
        sc.w = a.w + cc.w + s3n.w + b;
        sc.x = sc.x > 0.f ? sc.x : 0.2f * sc.x;
        sc.y = sc.y > 0.f ? sc.y : 0.2f * sc.y;
        sc.z = sc.z > 0.f ? sc.z : 0.2f * sc.z;
        sc.w = sc.w > 0.f ? sc.w : 0.2f * sc.w;
        src_l[p] = s;
        es_l[p * 4 + 0] = __expf(sc.x);
        es_l[p * 4 + 1] = __expf(sc.y);
        es_l[p * 4 + 2] = __expf(sc.z);
        es_l[p * 4 + 3] = __expf(sc.w);
    }
    __syncthreads();
    float a0 = 0.f, a1 = 0.f, sum = 0.f;
    int i = 0;
    for (; i + 4 <= tot; i += 4) {
        int q0 = src_l[i], q1 = src_l[i + 1], q2 = src_l[i + 2], q3 = src_l[i + 3];
        float e0 = es_l[i * 4 + hh], e1 = es_l[(i + 1) * 4 + hh];
        float e2 = es_l[(i + 2) * 4 + hh], e3 = es_l[(i + 3) * 4 + hh];
        unsigned v0 = *(const unsigned*)&h16[(size_t)q0 * DIM + 2 * t];
        unsigned v1 = *(const unsigned*)&h16[(size_t)q1 * DIM + 2 * t];
        unsigned v2 = *(const unsigned*)&h16[(size_t)q2 * DIM + 2 * t];
        unsigned v3 = *(const unsigned*)&h16[(size_t)q3 * DIM + 2 * t];
        sum += (e0 + e1) + (e2 + e3);
        a0 += e0 * bf2f((unsigned short)v0);
        a1 += e0 * bf2f((unsigned short)(v0 >> 16));
        a0 += e1 * bf2f((unsigned short)v1);
        a1 += e1 * bf2f((unsigned short)(v1 >> 16));
        a0 += e2 * bf2f((unsigned short)v2);
        a1 += e2 * bf2f((unsigned short)(v2 >> 16));
        a0 += e3 * bf2f((unsigned short)v3);
        a1 += e3 * bf2f((unsigned short)(v3 >> 16));
    }
    for (; i < tot; ++i) {
        int s = src_l[i];
        float e = es_l[i * 4 + hh];
        unsigned v = *(const unsigned*)&h16[(size_t)s * DIM + 2 * t];
        sum += e;
        a0 += e * bf2f((unsigned short)v);
        a1 += e * bf2f((unsigned short)(v >> 16));
    }
    float inv = 1.f / (sum + 1e-8f);
    *(float2*)&out[(size_t)n * DIM + 2 * t] = make_float2(a0 * inv, a1 * inv);
}

extern "C" void kernel_launch(void* const* d_in, const int* in_sizes, int n_in,
                              void* d_out, int out_size, void* d_ws, size_t ws_size,
                              hipStream_t stream) {
    const float* ent = (const float*)d_in[0];
    const float* rel = (const float*)d_in[1];
    const int* ei = (const int*)d_in[2];   // [2,E]: src then dst
    const int* et = (const int*)d_in[3];   // [E]
    const float* W = (const float*)d_in[4];
    const float* Wr = (const float*)d_in[5];
    const float* aw = (const float*)d_in[6];
    const float* ab = (const float*)d_in[7];

    int N = in_sizes[0] / DIM;
    int R = in_sizes[1] / DIM;
    int E = in_sizes[3];
    int NBR = (N + 63) / 64;           // MFMA row blocks (625)
    int EB = (E + 1023) / 1024;        // edge blocks (625), 1024 edges each

    // workspace layout (16B-aligned chunks)
    char* w = (char*)d_ws;
    unsigned short* W16 = (unsigned short*)w;   w += (size_t)DIM * DIM * 2;
    unsigned short* h16 = (unsigned short*)w;   w += ((size_t)N * DIM * 2 + 15) / 16 * 16;
    float* s1 = (float*)w;     w += (size_t)N * HEADS * 4;
    float* s3 = (float*)w;     w += (size_t)N * HEADS * 4;
    float* s2 = (float*)w;     w += ((size_t)R * HEADS * 4 + 15) / 16 * 16;
    int* cnt = (int*)w;        w += (size_t)NG * N * 4;
    int* packed = (int*)w;     w += (size_t)NG * N * CAPG * 4;

    float* out = (float*)d_out;

    (void)hipMemsetAsync(cnt, 0, (size_t)NG * N * 4, stream);

    k_cvtW<<<16, 256, 0, stream>>>(W, W16);
    k_proj<<<NBR + EB, 256, 0, stream>>>(ent, W16, aw, ei, et, h16, (float4*)s1,
                                         (float4*)s3, cnt, packed, N, E, NBR);
    k_s2<<<(R * HEADS + 3) / 4, 256, 0, stream>>>(rel, Wr, aw, s2, R * HEADS);
    k_out<<<N, 64, 0, stream>>>(packed, cnt, (const float4*)s1, (const float4*)s2,
                                (const float4*)s3, ab, h16, out, N);
}